// Round 12
// baseline (207.820 us; speedup 1.0000x reference)
//
#include <hip/hip_runtime.h>

#define NN 100000
#define NE 1600000
#define RSH 9                  // 512 nodes per region
#define NR ((NN + 511) >> 9)   // 196 regions
#define TILE 4096
#define NTB ((NE + TILE - 1) / TILE)  // 391 tiles
#define RCAP 10496             // region capacity (mean 8163)

typedef _Float16 f16;
typedef _Float16 f16x8 __attribute__((ext_vector_type(8)));
typedef float f32x4 __attribute__((ext_vector_type(4)));
typedef float f32x2 __attribute__((ext_vector_type(2)));

static __device__ __forceinline__ float h2f_lo(unsigned v) {
    return (float)__builtin_bit_cast(_Float16, (unsigned short)(v & 0xffffu));
}
static __device__ __forceinline__ float h2f_hi(unsigned v) {
    return (float)__builtin_bit_cast(_Float16, (unsigned short)(v >> 16));
}
static __device__ __forceinline__ unsigned f2h_bits(float f) {
    return (unsigned)__builtin_bit_cast(unsigned short, (_Float16)f);
}

// ---------------- front mega-kernel: cvt x (f16 + fp8), build Wc1/Wc2, region hist ----------------

#define NBX 6250
#define NBW1 16
#define NBW2 8

__launch_bounds__(256)
__global__ void k_front(const float* __restrict__ x, f16* __restrict__ xb,
                        unsigned char* __restrict__ x8,
                        const float* __restrict__ w_l1, const float* __restrict__ w_r1,
                        f16* __restrict__ Wc1,
                        const float* __restrict__ w_l2, const float* __restrict__ w_r2,
                        f16* __restrict__ Wc2,
                        const int* __restrict__ dst, int* __restrict__ rhist) {
    __shared__ int lcnt[NR];
    int b = blockIdx.x, t = threadIdx.x;
    if (b < NBX) {
        int i = b * 2048 + t * 8;            // NN*128 = 12.8M = 6250*2048 exact
        float4 a = *(const float4*)(x + i);
        float4 c = *(const float4*)(x + i + 4);
        f16x8 v = { (f16)a.x, (f16)a.y, (f16)a.z, (f16)a.w,
                    (f16)c.x, (f16)c.y, (f16)c.z, (f16)c.w };
        *(f16x8*)(xb + i) = v;
        unsigned lo = __builtin_amdgcn_cvt_pk_fp8_f32(a.x, a.y, 0u, false);
        lo = __builtin_amdgcn_cvt_pk_fp8_f32(a.z, a.w, lo, true);
        unsigned hi = __builtin_amdgcn_cvt_pk_fp8_f32(c.x, c.y, 0u, false);
        hi = __builtin_amdgcn_cvt_pk_fp8_f32(c.z, c.w, hi, true);
        uint2 pk = make_uint2(lo, hi);
        *(uint2*)(x8 + i) = pk;
    } else if (b < NBX + NBW1) {
        int u = (b - NBX) * 2048 + t * 8;
        int o = u >> 8, k = u & 255;
        const float* srcp = (k < 128) ? (w_l1 + o * 128 + k) : (w_r1 + o * 128 + k - 128);
        float4 a = *(const float4*)(srcp);
        float4 c = *(const float4*)(srcp + 4);
        f16x8 v = { (f16)a.x, (f16)a.y, (f16)a.z, (f16)a.w,
                    (f16)c.x, (f16)c.y, (f16)c.z, (f16)c.w };
        *(f16x8*)(Wc1 + u) = v;
    } else if (b < NBX + NBW1 + NBW2) {
        int u = (b - NBX - NBW1) * 2048 + t * 8;
        int o = u >> 7, k = u & 127;
        const float* srcp = (o < 64) ? (w_l2 + o * 128 + k) : (w_r2 + (o - 64) * 128 + k);
        float4 a = *(const float4*)(srcp);
        float4 c = *(const float4*)(srcp + 4);
        f16x8 v = { (f16)a.x, (f16)a.y, (f16)a.z, (f16)a.w,
                    (f16)c.x, (f16)c.y, (f16)c.z, (f16)c.w };
        *(f16x8*)(Wc2 + u) = v;
    } else {
        int tb = b - NBX - NBW1 - NBW2;
        for (int i = t; i < NR; i += 256) lcnt[i] = 0;
        __syncthreads();
        int base = tb * TILE;
        int end = min(NE, base + TILE);
        for (int i = base + t; i < end; i += 256)
            atomicAdd(&lcnt[dst[i] >> RSH], 1);
        __syncthreads();
        for (int i = t; i < NR; i += 256)
            if (lcnt[i]) atomicAdd(&rhist[i], lcnt[i]);
    }
}

// ---------------- region scan ----------------

__global__ void k_rscan(const int* __restrict__ rhist, int* __restrict__ rstart,
                        int* __restrict__ rcursor, int* __restrict__ offs) {
    __shared__ int sh[256];
    int t = threadIdx.x;
    int v = (t < NR) ? rhist[t] : 0;
    sh[t] = v;
    __syncthreads();
    for (int off = 1; off < 256; off <<= 1) {
        int x = (t >= off) ? sh[t - off] : 0;
        __syncthreads();
        sh[t] += x;
        __syncthreads();
    }
    int excl = sh[t] - v;
    if (t < NR) { rstart[t] = excl; rcursor[t] = excl; }
    if (t == NR - 1) { rstart[NR] = excl + v; offs[NN] = NE; }
}

// ---------------- pass A: tile-reserved region scatter ----------------

__launch_bounds__(256)
__global__ void k_passA(const int* __restrict__ src, const int* __restrict__ dst,
                        int* __restrict__ rcursor, unsigned* __restrict__ pairs, int E) {
    __shared__ int lcnt[NR];
    __shared__ int lbase[NR];
    int t = threadIdx.x;
    int base = blockIdx.x * TILE;
    int end = min(E, base + TILE);
    for (int i = t; i < NR; i += 256) lcnt[i] = 0;
    __syncthreads();
    for (int i = base + t; i < end; i += 256)
        atomicAdd(&lcnt[dst[i] >> RSH], 1);
    __syncthreads();
    for (int i = t; i < NR; i += 256) {
        int c = lcnt[i];
        lbase[i] = c ? atomicAdd(&rcursor[i], c) : 0;
        lcnt[i] = 0;
    }
    __syncthreads();
    for (int i = base + t; i < end; i += 256) {
        int d = dst[i];
        int r = d >> RSH;
        int p = lbase[r] + atomicAdd(&lcnt[r], 1);
        pairs[p] = (unsigned)src[i] | ((unsigned)(d & 511) << 17);
    }
}

// ---------------- pass B: per-region LDS counting sort ----------------

__launch_bounds__(256)
__global__ void k_passB(const unsigned* __restrict__ pairs, const int* __restrict__ rstart,
                        int* __restrict__ csr, int* __restrict__ offs) {
    __shared__ unsigned buf[RCAP];
    __shared__ int buf2[RCAP];
    __shared__ int cnt[512];
    __shared__ int sc[256];
    int r = blockIdx.x, t = threadIdx.x;
    int s = rstart[r], e = rstart[r + 1];
    int n = e - s;
    for (int i = t; i < 512; i += 256) cnt[i] = 0;
    for (int i = t; i < n; i += 256) buf[i] = pairs[s + i];
    __syncthreads();
    for (int i = t; i < n; i += 256)
        atomicAdd(&cnt[(buf[i] >> 17) & 511], 1);
    __syncthreads();
    int c0 = cnt[2 * t], c1 = cnt[2 * t + 1];
    int mysum = c0 + c1;
    sc[t] = mysum;
    __syncthreads();
    for (int off = 1; off < 256; off <<= 1) {
        int x = (t >= off) ? sc[t - off] : 0;
        __syncthreads();
        sc[t] += x;
        __syncthreads();
    }
    int base0 = sc[t] - mysum;
    cnt[2 * t] = base0;
    cnt[2 * t + 1] = base0 + c0;
    int node = (r << RSH) + 2 * t;
    if (node < NN)     offs[node]     = s + base0;
    if (node + 1 < NN) offs[node + 1] = s + base0 + c0;
    __syncthreads();
    for (int i = t; i < n; i += 256) {
        unsigned u = buf[i];
        int p = atomicAdd(&cnt[(u >> 17) & 511], 1);
        buf2[p] = (int)(u & 0x1FFFF);
    }
    __syncthreads();
    for (int i = t; i < n; i += 256) csr[s + i] = buf2[i];
}

// ---------------- aggx: mean-agg of x8 (fp8 128B rows), quarter-wave per edge ----------------
// f32x2 accumulators (v_pk_add_f32), 4 rows in flight per lane (16 edges/wave-iter).

__launch_bounds__(256)
__global__ void k_aggx(const unsigned char* __restrict__ x8, unsigned* __restrict__ aggx,
                       const int* __restrict__ csr, const int* __restrict__ offs) {
    int node = blockIdx.x * 4 + (threadIdx.x >> 6);
    if (node >= NN) return;
    int lane = threadIdx.x & 63;
    int q = lane >> 4, fl = lane & 15;
    int s = offs[node], e = offs[node + 1];
    f32x2 c01 = {0.f, 0.f}, c23 = {0.f, 0.f}, c45 = {0.f, 0.f}, c67 = {0.f, 0.f};

    int i = s + q;
    for (; i + 12 < e; i += 16) {            // 4 rows/lane, 16 edges/wave
        int s0 = csr[i], s1 = csr[i + 4], s2 = csr[i + 8], s3 = csr[i + 12];
        uint2 v0 = *(const uint2*)(x8 + (size_t)s0 * 128 + fl * 8);
        uint2 v1 = *(const uint2*)(x8 + (size_t)s1 * 128 + fl * 8);
        uint2 v2 = *(const uint2*)(x8 + (size_t)s2 * 128 + fl * 8);
        uint2 v3 = *(const uint2*)(x8 + (size_t)s3 * 128 + fl * 8);
        c01 += __builtin_amdgcn_cvt_pk_f32_fp8(v0.x, false);
        c23 += __builtin_amdgcn_cvt_pk_f32_fp8(v0.x, true);
        c45 += __builtin_amdgcn_cvt_pk_f32_fp8(v0.y, false);
        c67 += __builtin_amdgcn_cvt_pk_f32_fp8(v0.y, true);
        c01 += __builtin_amdgcn_cvt_pk_f32_fp8(v1.x, false);
        c23 += __builtin_amdgcn_cvt_pk_f32_fp8(v1.x, true);
        c45 += __builtin_amdgcn_cvt_pk_f32_fp8(v1.y, false);
        c67 += __builtin_amdgcn_cvt_pk_f32_fp8(v1.y, true);
        c01 += __builtin_amdgcn_cvt_pk_f32_fp8(v2.x, false);
        c23 += __builtin_amdgcn_cvt_pk_f32_fp8(v2.x, true);
        c45 += __builtin_amdgcn_cvt_pk_f32_fp8(v2.y, false);
        c67 += __builtin_amdgcn_cvt_pk_f32_fp8(v2.y, true);
        c01 += __builtin_amdgcn_cvt_pk_f32_fp8(v3.x, false);
        c23 += __builtin_amdgcn_cvt_pk_f32_fp8(v3.x, true);
        c45 += __builtin_amdgcn_cvt_pk_f32_fp8(v3.y, false);
        c67 += __builtin_amdgcn_cvt_pk_f32_fp8(v3.y, true);
    }
    for (; i < e; i += 4) {
        int s0 = csr[i];
        uint2 v0 = *(const uint2*)(x8 + (size_t)s0 * 128 + fl * 8);
        c01 += __builtin_amdgcn_cvt_pk_f32_fp8(v0.x, false);
        c23 += __builtin_amdgcn_cvt_pk_f32_fp8(v0.x, true);
        c45 += __builtin_amdgcn_cvt_pk_f32_fp8(v0.y, false);
        c67 += __builtin_amdgcn_cvt_pk_f32_fp8(v0.y, true);
    }

    float a0 = c01[0], a1 = c01[1], a2 = c23[0], a3 = c23[1];
    float a4 = c45[0], a5 = c45[1], a6 = c67[0], a7 = c67[1];
    a0 += __shfl_xor(a0, 16, 64); a1 += __shfl_xor(a1, 16, 64);
    a2 += __shfl_xor(a2, 16, 64); a3 += __shfl_xor(a3, 16, 64);
    a4 += __shfl_xor(a4, 16, 64); a5 += __shfl_xor(a5, 16, 64);
    a6 += __shfl_xor(a6, 16, 64); a7 += __shfl_xor(a7, 16, 64);
    a0 += __shfl_xor(a0, 32, 64); a1 += __shfl_xor(a1, 32, 64);
    a2 += __shfl_xor(a2, 32, 64); a3 += __shfl_xor(a3, 32, 64);
    a4 += __shfl_xor(a4, 32, 64); a5 += __shfl_xor(a5, 32, 64);
    a6 += __shfl_xor(a6, 32, 64); a7 += __shfl_xor(a7, 32, 64);

    if (lane < 16) {
        float inv = 1.0f / fmaxf((float)(e - s), 1.0f);
        uint4 w;
        w.x = f2h_bits(a0 * inv) | (f2h_bits(a1 * inv) << 16);
        w.y = f2h_bits(a2 * inv) | (f2h_bits(a3 * inv) << 16);
        w.z = f2h_bits(a4 * inv) | (f2h_bits(a5 * inv) << 16);
        w.w = f2h_bits(a6 * inv) | (f2h_bits(a7 * inv) << 16);
        *(uint4*)(aggx + (size_t)node * 64 + fl * 4) = w;
    }
}

// ---------------- fused GEMM1+GEMM2 (unchanged) ----------------

__launch_bounds__(256)
__global__ void k_gemm12(const f16* __restrict__ aggx, const f16* __restrict__ xb,
                         const f16* __restrict__ Wc1, const float* __restrict__ b1,
                         const f16* __restrict__ Wc2, const float* __restrict__ b2,
                         f16* __restrict__ hl2h, unsigned char* __restrict__ hl28,
                         f16* __restrict__ outr16, int M) {
    __shared__ __align__(16) char wlds[128 * 272];
    __shared__ __align__(16) char hlds[64 * 272];
    int t = threadIdx.x;
    int l = t & 63;
    int wid = t >> 6;
    int bm = blockIdx.x * 64;
    int arow = bm + wid * 16 + (l & 15);
    if (arow >= M) arow = M - 1;
    int kq = (l >> 4) * 8;
    int col = l & 15;
    int lrow0 = wid * 16 + ((l >> 4) << 2);
    int lrowA = wid * 16 + (l & 15);

    f32x4 acc1[8];
    #pragma unroll
    for (int n = 0; n < 8; ++n) acc1[n] = (f32x4){0.f, 0.f, 0.f, 0.f};

    #pragma unroll
    for (int half = 0; half < 2; ++half) {
        __syncthreads();
        for (int u = t; u < 2048; u += 256) {
            int r = u >> 4, c = u & 15;
            *(uint4*)(wlds + r * 272 + c * 16) =
                *(const uint4*)(Wc1 + (size_t)r * 256 + half * 128 + c * 8);
        }
        __syncthreads();
        const f16* A = half ? xb : aggx;
        #pragma unroll
        for (int ks = 0; ks < 4; ++ks) {
            f16x8 av = *(const f16x8*)(A + (size_t)arow * 128 + ks * 32 + kq);
            #pragma unroll
            for (int n = 0; n < 8; ++n) {
                f16x8 bv = *(const f16x8*)(wlds + (n * 16 + (l & 15)) * 272 + ks * 64 + kq * 2);
                acc1[n] = __builtin_amdgcn_mfma_f32_16x16x32_f16(av, bv, acc1[n], 0, 0, 0);
            }
        }
    }

    __syncthreads();
    #pragma unroll
    for (int n = 0; n < 8; ++n) {
        float bvb = b1[n * 16 + col];
        #pragma unroll
        for (int r = 0; r < 4; ++r) {
            f16 hv = (f16)fmaxf(acc1[n][r] + bvb, 0.f);
            *(f16*)(hlds + (lrow0 + r) * 272 + (n * 16 + col) * 2) = hv;
        }
    }
    __syncthreads();

    for (int u = t; u < 2048; u += 256) {
        int r = u >> 4, c = u & 15;
        *(uint4*)(wlds + r * 272 + c * 16) = *(const uint4*)(Wc2 + (size_t)r * 128 + c * 8);
    }
    __syncthreads();

    f32x4 acc2[8];
    #pragma unroll
    for (int n = 0; n < 8; ++n) acc2[n] = (f32x4){0.f, 0.f, 0.f, 0.f};
    #pragma unroll
    for (int ks = 0; ks < 4; ++ks) {
        f16x8 av = *(const f16x8*)(hlds + lrowA * 272 + (ks * 32 + kq) * 2);
        #pragma unroll
        for (int n = 0; n < 8; ++n) {
            f16x8 bv = *(const f16x8*)(wlds + (n * 16 + (l & 15)) * 272 + ks * 64 + kq * 2);
            acc2[n] = __builtin_amdgcn_mfma_f32_16x16x32_f16(av, bv, acc2[n], 0, 0, 0);
        }
    }

    int row0g = bm + lrow0;
    #pragma unroll
    for (int n = 0; n < 4; ++n) {
        #pragma unroll
        for (int r = 0; r < 4; ++r) {
            int gr = row0g + r;
            if (gr < M) hl2h[(size_t)gr * 64 + n * 16 + col] = (f16)acc2[n][r];
        }
    }
    #pragma unroll
    for (int n = 4; n < 8; ++n) {
        float bvb = b2[(n - 4) * 16 + col];
        #pragma unroll
        for (int r = 0; r < 4; ++r) {
            int gr = row0g + r;
            if (gr < M) outr16[(size_t)gr * 64 + (n - 4) * 16 + col] = (f16)(acc2[n][r] + bvb);
        }
    }
    __syncthreads();
    #pragma unroll
    for (int n = 0; n < 4; ++n) {
        #pragma unroll
        for (int r = 0; r < 4; ++r) {
            unsigned pk = __builtin_amdgcn_cvt_pk_fp8_f32(acc2[n][r], acc2[n][r], 0u, false);
            *(unsigned char*)(hlds + (lrow0 + r) * 64 + n * 16 + col) = (unsigned char)(pk & 0xFF);
        }
    }
    __syncthreads();
    {
        int rr = t >> 2, seg = t & 3;
        int gr = bm + rr;
        if (gr < M)
            *(uint4*)(hl28 + (size_t)gr * 64 + seg * 16) = *(const uint4*)(hlds + rr * 64 + seg * 16);
    }
}

// ---------------- agg2 final: quarter-wave per edge, f32x2 accum, 4 rows in flight ----------------

__launch_bounds__(256)
__global__ void k_agg2f(const unsigned char* __restrict__ hl28,
                        const f16* __restrict__ hl2,
                        const f16* __restrict__ outr,
                        float* __restrict__ out,
                        const int* __restrict__ csr, const int* __restrict__ offs) {
    int node = blockIdx.x * 4 + (threadIdx.x >> 6);
    if (node >= NN) return;
    int lane = threadIdx.x & 63;
    int q = lane >> 4, fl = lane & 15;
    int s = offs[node], e = offs[node + 1];
    int deg = e - s;
    f32x2 c01 = {0.f, 0.f}, c23 = {0.f, 0.f};

    if (deg >= 6) {
        int i = s + q;
        for (; i + 12 < e; i += 16) {        // 4 rows/lane, 16 edges/wave
            int s0 = csr[i], s1 = csr[i + 4], s2 = csr[i + 8], s3 = csr[i + 12];
            unsigned v0 = *(const unsigned*)(hl28 + (size_t)s0 * 64 + fl * 4);
            unsigned v1 = *(const unsigned*)(hl28 + (size_t)s1 * 64 + fl * 4);
            unsigned v2 = *(const unsigned*)(hl28 + (size_t)s2 * 64 + fl * 4);
            unsigned v3 = *(const unsigned*)(hl28 + (size_t)s3 * 64 + fl * 4);
            c01 += __builtin_amdgcn_cvt_pk_f32_fp8(v0, false);
            c23 += __builtin_amdgcn_cvt_pk_f32_fp8(v0, true);
            c01 += __builtin_amdgcn_cvt_pk_f32_fp8(v1, false);
            c23 += __builtin_amdgcn_cvt_pk_f32_fp8(v1, true);
            c01 += __builtin_amdgcn_cvt_pk_f32_fp8(v2, false);
            c23 += __builtin_amdgcn_cvt_pk_f32_fp8(v2, true);
            c01 += __builtin_amdgcn_cvt_pk_f32_fp8(v3, false);
            c23 += __builtin_amdgcn_cvt_pk_f32_fp8(v3, true);
        }
        for (; i < e; i += 4) {
            unsigned v0 = *(const unsigned*)(hl28 + (size_t)csr[i] * 64 + fl * 4);
            c01 += __builtin_amdgcn_cvt_pk_f32_fp8(v0, false);
            c23 += __builtin_amdgcn_cvt_pk_f32_fp8(v0, true);
        }
    } else {
        int i = s + q;
        for (; i < e; i += 4) {
            uint2 v = *(const uint2*)(hl2 + (size_t)csr[i] * 64 + fl * 4);
            c01 += (f32x2){h2f_lo(v.x), h2f_hi(v.x)};
            c23 += (f32x2){h2f_lo(v.y), h2f_hi(v.y)};
        }
    }

    float a0 = c01[0], a1 = c01[1], a2 = c23[0], a3 = c23[1];
    a0 += __shfl_xor(a0, 16, 64); a1 += __shfl_xor(a1, 16, 64);
    a2 += __shfl_xor(a2, 16, 64); a3 += __shfl_xor(a3, 16, 64);
    a0 += __shfl_xor(a0, 32, 64); a1 += __shfl_xor(a1, 32, 64);
    a2 += __shfl_xor(a2, 32, 64); a3 += __shfl_xor(a3, 32, 64);

    if (lane < 16) {
        float inv = 1.0f / fmaxf((float)deg, 1.0f);
        uint2 ro = *(const uint2*)(outr + (size_t)node * 64 + fl * 4);
        float4 o;
        o.x = fmaf(a0, inv, h2f_lo(ro.x));
        o.y = fmaf(a1, inv, h2f_hi(ro.x));
        o.z = fmaf(a2, inv, h2f_lo(ro.y));
        o.w = fmaf(a3, inv, h2f_hi(ro.y));
        *(float4*)(out + (size_t)node * 64 + fl * 4) = o;
    }
}

// ---------------- launch ----------------

extern "C" void kernel_launch(void* const* d_in, const int* in_sizes, int n_in,
                              void* d_out, int out_size, void* d_ws, size_t ws_size,
                              hipStream_t stream) {
    const float* x    = (const float*)d_in[0];
    const int* ei     = (const int*)d_in[1];   // int64 ref -> int32 at the harness boundary
    const float* w_l1 = (const float*)d_in[2];
    const float* w_r1 = (const float*)d_in[3];
    const float* b1   = (const float*)d_in[4];
    const float* w_l2 = (const float*)d_in[5];
    const float* w_r2 = (const float*)d_in[6];
    const float* b2   = (const float*)d_in[7];
    float* out        = (float*)d_out;

    const int* esrc = ei;
    const int* edst = ei + NE;

    // workspace layout (~110 MB)
    f16* xb     = (f16*)d_ws;                         // NN*128
    f16* aggx   = xb + (size_t)NN * 128;              // NN*128
    f16* hl2h   = aggx + (size_t)NN * 128;            // NN*64
    f16* outr16 = hl2h + (size_t)NN * 64;             // NN*64
    f16* Wc1    = outr16 + (size_t)NN * 64;           // 128*256
    f16* Wc2    = Wc1 + 128 * 256;                    // 128*128
    unsigned char* x8   = (unsigned char*)(Wc2 + 128 * 128);  // NN*128 fp8
    unsigned char* hl28 = x8 + (size_t)NN * 128;               // NN*64 fp8
    unsigned* pairs = (unsigned*)(hl28 + (size_t)NN * 64);     // NE
    int* csr    = (int*)(pairs + NE);                 // NE
    int* offs   = csr + NE;                           // NN+1
    int* rhist  = offs + NN + 1;                      // NR
    int* rstart = rhist + NR;                         // NR+1
    int* rcursor= rstart + NR + 1;                    // NR

    // ---- front: cvt x (f16+fp8) + build Wc1/Wc2 + region hist ----
    hipMemsetAsync(rhist, 0, NR * sizeof(int), stream);
    k_front<<<NBX + NBW1 + NBW2 + NTB, 256, 0, stream>>>(
        x, xb, x8, w_l1, w_r1, Wc1, w_l2, w_r2, Wc2, edst, rhist);

    // ---- CSR: scan -> tile-reserved scatter -> LDS sort ----
    k_rscan<<<1, 256, 0, stream>>>(rhist, rstart, rcursor, offs);
    k_passA<<<NTB, 256, 0, stream>>>(esrc, edst, rcursor, pairs, NE);
    k_passB<<<NR, 256, 0, stream>>>(pairs, rstart, csr, offs);

    // ---- layer 1 agg + fused GEMMs ----
    k_aggx<<<(NN + 3) / 4, 256, 0, stream>>>(x8, (unsigned*)aggx, csr, offs);
    k_gemm12<<<(NN + 63) / 64, 256, 0, stream>>>(aggx, xb, Wc1, b1, Wc2, b2,
                                                 hl2h, hl28, outr16, NN);

    // ---- layer 2 agg + combine ----
    k_agg2f<<<(NN + 3) / 4, 256, 0, stream>>>(hl28, hl2h, outr16, out, csr, offs);
}

// Round 13
// 187.560 us; speedup vs baseline: 1.1080x; 1.1080x over previous
//
#include <hip/hip_runtime.h>

#define NN 100000
#define NE 1600000
#define RSH 9                  // 512 nodes per region
#define NR ((NN + 511) >> 9)   // 196 regions
#define TILE 4096
#define NTB ((NE + TILE - 1) / TILE)  // 391 tiles
#define RCAP 10496             // region capacity (mean 8163)
#define NAGB 2048              // persistent agg blocks
#define NAGW (NAGB * 4)        // persistent agg waves

typedef _Float16 f16;
typedef _Float16 f16x8 __attribute__((ext_vector_type(8)));
typedef float f32x4 __attribute__((ext_vector_type(4)));
typedef float f32x2 __attribute__((ext_vector_type(2)));

static __device__ __forceinline__ float h2f_lo(unsigned v) {
    return (float)__builtin_bit_cast(_Float16, (unsigned short)(v & 0xffffu));
}
static __device__ __forceinline__ float h2f_hi(unsigned v) {
    return (float)__builtin_bit_cast(_Float16, (unsigned short)(v >> 16));
}
static __device__ __forceinline__ unsigned f2h_bits(float f) {
    return (unsigned)__builtin_bit_cast(unsigned short, (_Float16)f);
}

// ---------------- front mega-kernel: cvt x (f16 + fp8), build Wc1/Wc2, region hist ----------------

#define NBX 6250
#define NBW1 16
#define NBW2 8

__launch_bounds__(256)
__global__ void k_front(const float* __restrict__ x, f16* __restrict__ xb,
                        unsigned char* __restrict__ x8,
                        const float* __restrict__ w_l1, const float* __restrict__ w_r1,
                        f16* __restrict__ Wc1,
                        const float* __restrict__ w_l2, const float* __restrict__ w_r2,
                        f16* __restrict__ Wc2,
                        const int* __restrict__ dst, int* __restrict__ rhist) {
    __shared__ int lcnt[NR];
    int b = blockIdx.x, t = threadIdx.x;
    if (b < NBX) {
        int i = b * 2048 + t * 8;            // NN*128 = 12.8M = 6250*2048 exact
        float4 a = *(const float4*)(x + i);
        float4 c = *(const float4*)(x + i + 4);
        f16x8 v = { (f16)a.x, (f16)a.y, (f16)a.z, (f16)a.w,
                    (f16)c.x, (f16)c.y, (f16)c.z, (f16)c.w };
        *(f16x8*)(xb + i) = v;
        unsigned lo = __builtin_amdgcn_cvt_pk_fp8_f32(a.x, a.y, 0u, false);
        lo = __builtin_amdgcn_cvt_pk_fp8_f32(a.z, a.w, lo, true);
        unsigned hi = __builtin_amdgcn_cvt_pk_fp8_f32(c.x, c.y, 0u, false);
        hi = __builtin_amdgcn_cvt_pk_fp8_f32(c.z, c.w, hi, true);
        uint2 pk = make_uint2(lo, hi);
        *(uint2*)(x8 + i) = pk;
    } else if (b < NBX + NBW1) {
        int u = (b - NBX) * 2048 + t * 8;
        int o = u >> 8, k = u & 255;
        const float* srcp = (k < 128) ? (w_l1 + o * 128 + k) : (w_r1 + o * 128 + k - 128);
        float4 a = *(const float4*)(srcp);
        float4 c = *(const float4*)(srcp + 4);
        f16x8 v = { (f16)a.x, (f16)a.y, (f16)a.z, (f16)a.w,
                    (f16)c.x, (f16)c.y, (f16)c.z, (f16)c.w };
        *(f16x8*)(Wc1 + u) = v;
    } else if (b < NBX + NBW1 + NBW2) {
        int u = (b - NBX - NBW1) * 2048 + t * 8;
        int o = u >> 7, k = u & 127;
        const float* srcp = (o < 64) ? (w_l2 + o * 128 + k) : (w_r2 + (o - 64) * 128 + k);
        float4 a = *(const float4*)(srcp);
        float4 c = *(const float4*)(srcp + 4);
        f16x8 v = { (f16)a.x, (f16)a.y, (f16)a.z, (f16)a.w,
                    (f16)c.x, (f16)c.y, (f16)c.z, (f16)c.w };
        *(f16x8*)(Wc2 + u) = v;
    } else {
        int tb = b - NBX - NBW1 - NBW2;
        for (int i = t; i < NR; i += 256) lcnt[i] = 0;
        __syncthreads();
        int base = tb * TILE;
        int end = min(NE, base + TILE);
        for (int i = base + t; i < end; i += 256)
            atomicAdd(&lcnt[dst[i] >> RSH], 1);
        __syncthreads();
        for (int i = t; i < NR; i += 256)
            if (lcnt[i]) atomicAdd(&rhist[i], lcnt[i]);
    }
}

// ---------------- region scan ----------------

__global__ void k_rscan(const int* __restrict__ rhist, int* __restrict__ rstart,
                        int* __restrict__ rcursor, int* __restrict__ offs) {
    __shared__ int sh[256];
    int t = threadIdx.x;
    int v = (t < NR) ? rhist[t] : 0;
    sh[t] = v;
    __syncthreads();
    for (int off = 1; off < 256; off <<= 1) {
        int x = (t >= off) ? sh[t - off] : 0;
        __syncthreads();
        sh[t] += x;
        __syncthreads();
    }
    int excl = sh[t] - v;
    if (t < NR) { rstart[t] = excl; rcursor[t] = excl; }
    if (t == NR - 1) { rstart[NR] = excl + v; offs[NN] = NE; }
}

// ---------------- pass A: tile-reserved region scatter ----------------

__launch_bounds__(256)
__global__ void k_passA(const int* __restrict__ src, const int* __restrict__ dst,
                        int* __restrict__ rcursor, unsigned* __restrict__ pairs, int E) {
    __shared__ int lcnt[NR];
    __shared__ int lbase[NR];
    int t = threadIdx.x;
    int base = blockIdx.x * TILE;
    int end = min(E, base + TILE);
    for (int i = t; i < NR; i += 256) lcnt[i] = 0;
    __syncthreads();
    for (int i = base + t; i < end; i += 256)
        atomicAdd(&lcnt[dst[i] >> RSH], 1);
    __syncthreads();
    for (int i = t; i < NR; i += 256) {
        int c = lcnt[i];
        lbase[i] = c ? atomicAdd(&rcursor[i], c) : 0;
        lcnt[i] = 0;
    }
    __syncthreads();
    for (int i = base + t; i < end; i += 256) {
        int d = dst[i];
        int r = d >> RSH;
        int p = lbase[r] + atomicAdd(&lcnt[r], 1);
        pairs[p] = (unsigned)src[i] | ((unsigned)(d & 511) << 17);
    }
}

// ---------------- pass B: per-region LDS counting sort ----------------

__launch_bounds__(256)
__global__ void k_passB(const unsigned* __restrict__ pairs, const int* __restrict__ rstart,
                        int* __restrict__ csr, int* __restrict__ offs) {
    __shared__ unsigned buf[RCAP];
    __shared__ int buf2[RCAP];
    __shared__ int cnt[512];
    __shared__ int sc[256];
    int r = blockIdx.x, t = threadIdx.x;
    int s = rstart[r], e = rstart[r + 1];
    int n = e - s;
    for (int i = t; i < 512; i += 256) cnt[i] = 0;
    for (int i = t; i < n; i += 256) buf[i] = pairs[s + i];
    __syncthreads();
    for (int i = t; i < n; i += 256)
        atomicAdd(&cnt[(buf[i] >> 17) & 511], 1);
    __syncthreads();
    int c0 = cnt[2 * t], c1 = cnt[2 * t + 1];
    int mysum = c0 + c1;
    sc[t] = mysum;
    __syncthreads();
    for (int off = 1; off < 256; off <<= 1) {
        int x = (t >= off) ? sc[t - off] : 0;
        __syncthreads();
        sc[t] += x;
        __syncthreads();
    }
    int base0 = sc[t] - mysum;
    cnt[2 * t] = base0;
    cnt[2 * t + 1] = base0 + c0;
    int node = (r << RSH) + 2 * t;
    if (node < NN)     offs[node]     = s + base0;
    if (node + 1 < NN) offs[node + 1] = s + base0 + c0;
    __syncthreads();
    for (int i = t; i < n; i += 256) {
        unsigned u = buf[i];
        int p = atomicAdd(&cnt[(u >> 17) & 511], 1);
        buf2[p] = (int)(u & 0x1FFFF);
    }
    __syncthreads();
    for (int i = t; i < n; i += 256) csr[s + i] = buf2[i];
}

// ---------------- aggx: persistent waves, 2 nodes/wave interleaved (2 indep chains) ----------------
// quarter-wave per edge: q=lane>>4 edge phase, fl=lane&15 covers features 8fl..8fl+7 (uint2 fp8).

__launch_bounds__(256)
__global__ void k_aggx(const unsigned char* __restrict__ x8, unsigned* __restrict__ aggx,
                       const int* __restrict__ csr, const int* __restrict__ offs) {
    int wid = blockIdx.x * 4 + (threadIdx.x >> 6);
    int lane = threadIdx.x & 63;
    int q = lane >> 4, fl = lane & 15;

    for (int nA = wid * 2; nA < NN; nA += NAGW * 2) {     // NN even -> nA+1 always valid
        int sA = offs[nA], eA = offs[nA + 1], eB = offs[nA + 2];
        int sB = eA;

        f32x2 A0 = {0.f, 0.f}, A1 = {0.f, 0.f}, A2 = {0.f, 0.f}, A3 = {0.f, 0.f};
        f32x2 B0 = {0.f, 0.f}, B1 = {0.f, 0.f}, B2 = {0.f, 0.f}, B3 = {0.f, 0.f};

        int iA = sA + q, iB = sB + q;
        // fused main loop: 2-deep per node, two independent csr->row chains
        while (iA + 4 < eA && iB + 4 < eB) {
            int a0 = csr[iA], a1 = csr[iA + 4];
            int b0 = csr[iB], b1 = csr[iB + 4];
            uint2 va0 = *(const uint2*)(x8 + (size_t)a0 * 128 + fl * 8);
            uint2 va1 = *(const uint2*)(x8 + (size_t)a1 * 128 + fl * 8);
            uint2 vb0 = *(const uint2*)(x8 + (size_t)b0 * 128 + fl * 8);
            uint2 vb1 = *(const uint2*)(x8 + (size_t)b1 * 128 + fl * 8);
            A0 += __builtin_amdgcn_cvt_pk_f32_fp8(va0.x, false);
            A1 += __builtin_amdgcn_cvt_pk_f32_fp8(va0.x, true);
            A2 += __builtin_amdgcn_cvt_pk_f32_fp8(va0.y, false);
            A3 += __builtin_amdgcn_cvt_pk_f32_fp8(va0.y, true);
            A0 += __builtin_amdgcn_cvt_pk_f32_fp8(va1.x, false);
            A1 += __builtin_amdgcn_cvt_pk_f32_fp8(va1.x, true);
            A2 += __builtin_amdgcn_cvt_pk_f32_fp8(va1.y, false);
            A3 += __builtin_amdgcn_cvt_pk_f32_fp8(va1.y, true);
            B0 += __builtin_amdgcn_cvt_pk_f32_fp8(vb0.x, false);
            B1 += __builtin_amdgcn_cvt_pk_f32_fp8(vb0.x, true);
            B2 += __builtin_amdgcn_cvt_pk_f32_fp8(vb0.y, false);
            B3 += __builtin_amdgcn_cvt_pk_f32_fp8(vb0.y, true);
            B0 += __builtin_amdgcn_cvt_pk_f32_fp8(vb1.x, false);
            B1 += __builtin_amdgcn_cvt_pk_f32_fp8(vb1.x, true);
            B2 += __builtin_amdgcn_cvt_pk_f32_fp8(vb1.y, false);
            B3 += __builtin_amdgcn_cvt_pk_f32_fp8(vb1.y, true);
            iA += 8; iB += 8;
        }
        // leftover 2-deep single-node loops
        while (iA + 4 < eA) {
            int a0 = csr[iA], a1 = csr[iA + 4];
            uint2 va0 = *(const uint2*)(x8 + (size_t)a0 * 128 + fl * 8);
            uint2 va1 = *(const uint2*)(x8 + (size_t)a1 * 128 + fl * 8);
            A0 += __builtin_amdgcn_cvt_pk_f32_fp8(va0.x, false);
            A1 += __builtin_amdgcn_cvt_pk_f32_fp8(va0.x, true);
            A2 += __builtin_amdgcn_cvt_pk_f32_fp8(va0.y, false);
            A3 += __builtin_amdgcn_cvt_pk_f32_fp8(va0.y, true);
            A0 += __builtin_amdgcn_cvt_pk_f32_fp8(va1.x, false);
            A1 += __builtin_amdgcn_cvt_pk_f32_fp8(va1.x, true);
            A2 += __builtin_amdgcn_cvt_pk_f32_fp8(va1.y, false);
            A3 += __builtin_amdgcn_cvt_pk_f32_fp8(va1.y, true);
            iA += 8;
        }
        while (iB + 4 < eB) {
            int b0 = csr[iB], b1 = csr[iB + 4];
            uint2 vb0 = *(const uint2*)(x8 + (size_t)b0 * 128 + fl * 8);
            uint2 vb1 = *(const uint2*)(x8 + (size_t)b1 * 128 + fl * 8);
            B0 += __builtin_amdgcn_cvt_pk_f32_fp8(vb0.x, false);
            B1 += __builtin_amdgcn_cvt_pk_f32_fp8(vb0.x, true);
            B2 += __builtin_amdgcn_cvt_pk_f32_fp8(vb0.y, false);
            B3 += __builtin_amdgcn_cvt_pk_f32_fp8(vb0.y, true);
            B0 += __builtin_amdgcn_cvt_pk_f32_fp8(vb1.x, false);
            B1 += __builtin_amdgcn_cvt_pk_f32_fp8(vb1.x, true);
            B2 += __builtin_amdgcn_cvt_pk_f32_fp8(vb1.y, false);
            B3 += __builtin_amdgcn_cvt_pk_f32_fp8(vb1.y, true);
            iB += 8;
        }
        for (; iA < eA; iA += 4) {
            uint2 v = *(const uint2*)(x8 + (size_t)csr[iA] * 128 + fl * 8);
            A0 += __builtin_amdgcn_cvt_pk_f32_fp8(v.x, false);
            A1 += __builtin_amdgcn_cvt_pk_f32_fp8(v.x, true);
            A2 += __builtin_amdgcn_cvt_pk_f32_fp8(v.y, false);
            A3 += __builtin_amdgcn_cvt_pk_f32_fp8(v.y, true);
        }
        for (; iB < eB; iB += 4) {
            uint2 v = *(const uint2*)(x8 + (size_t)csr[iB] * 128 + fl * 8);
            B0 += __builtin_amdgcn_cvt_pk_f32_fp8(v.x, false);
            B1 += __builtin_amdgcn_cvt_pk_f32_fp8(v.x, true);
            B2 += __builtin_amdgcn_cvt_pk_f32_fp8(v.y, false);
            B3 += __builtin_amdgcn_cvt_pk_f32_fp8(v.y, true);
        }

        float a0 = A0[0], a1 = A0[1], a2 = A1[0], a3 = A1[1];
        float a4 = A2[0], a5 = A2[1], a6 = A3[0], a7 = A3[1];
        float b0 = B0[0], b1 = B0[1], b2 = B1[0], b3 = B1[1];
        float b4 = B2[0], b5 = B2[1], b6 = B3[0], b7 = B3[1];
        a0 += __shfl_xor(a0, 16, 64); a1 += __shfl_xor(a1, 16, 64);
        a2 += __shfl_xor(a2, 16, 64); a3 += __shfl_xor(a3, 16, 64);
        a4 += __shfl_xor(a4, 16, 64); a5 += __shfl_xor(a5, 16, 64);
        a6 += __shfl_xor(a6, 16, 64); a7 += __shfl_xor(a7, 16, 64);
        b0 += __shfl_xor(b0, 16, 64); b1 += __shfl_xor(b1, 16, 64);
        b2 += __shfl_xor(b2, 16, 64); b3 += __shfl_xor(b3, 16, 64);
        b4 += __shfl_xor(b4, 16, 64); b5 += __shfl_xor(b5, 16, 64);
        b6 += __shfl_xor(b6, 16, 64); b7 += __shfl_xor(b7, 16, 64);
        a0 += __shfl_xor(a0, 32, 64); a1 += __shfl_xor(a1, 32, 64);
        a2 += __shfl_xor(a2, 32, 64); a3 += __shfl_xor(a3, 32, 64);
        a4 += __shfl_xor(a4, 32, 64); a5 += __shfl_xor(a5, 32, 64);
        a6 += __shfl_xor(a6, 32, 64); a7 += __shfl_xor(a7, 32, 64);
        b0 += __shfl_xor(b0, 32, 64); b1 += __shfl_xor(b1, 32, 64);
        b2 += __shfl_xor(b2, 32, 64); b3 += __shfl_xor(b3, 32, 64);
        b4 += __shfl_xor(b4, 32, 64); b5 += __shfl_xor(b5, 32, 64);
        b6 += __shfl_xor(b6, 32, 64); b7 += __shfl_xor(b7, 32, 64);

        if (lane < 16) {
            float invA = 1.0f / fmaxf((float)(eA - sA), 1.0f);
            uint4 w;
            w.x = f2h_bits(a0 * invA) | (f2h_bits(a1 * invA) << 16);
            w.y = f2h_bits(a2 * invA) | (f2h_bits(a3 * invA) << 16);
            w.z = f2h_bits(a4 * invA) | (f2h_bits(a5 * invA) << 16);
            w.w = f2h_bits(a6 * invA) | (f2h_bits(a7 * invA) << 16);
            *(uint4*)(aggx + (size_t)nA * 64 + fl * 4) = w;
            float invB = 1.0f / fmaxf((float)(eB - sB), 1.0f);
            uint4 u;
            u.x = f2h_bits(b0 * invB) | (f2h_bits(b1 * invB) << 16);
            u.y = f2h_bits(b2 * invB) | (f2h_bits(b3 * invB) << 16);
            u.z = f2h_bits(b4 * invB) | (f2h_bits(b5 * invB) << 16);
            u.w = f2h_bits(b6 * invB) | (f2h_bits(b7 * invB) << 16);
            *(uint4*)(aggx + (size_t)(nA + 1) * 64 + fl * 4) = u;
        }
    }
}

// ---------------- fused GEMM1+GEMM2 (unchanged) ----------------

__launch_bounds__(256)
__global__ void k_gemm12(const f16* __restrict__ aggx, const f16* __restrict__ xb,
                         const f16* __restrict__ Wc1, const float* __restrict__ b1,
                         const f16* __restrict__ Wc2, const float* __restrict__ b2,
                         f16* __restrict__ hl2h, unsigned char* __restrict__ hl28,
                         f16* __restrict__ outr16, int M) {
    __shared__ __align__(16) char wlds[128 * 272];
    __shared__ __align__(16) char hlds[64 * 272];
    int t = threadIdx.x;
    int l = t & 63;
    int wid = t >> 6;
    int bm = blockIdx.x * 64;
    int arow = bm + wid * 16 + (l & 15);
    if (arow >= M) arow = M - 1;
    int kq = (l >> 4) * 8;
    int col = l & 15;
    int lrow0 = wid * 16 + ((l >> 4) << 2);
    int lrowA = wid * 16 + (l & 15);

    f32x4 acc1[8];
    #pragma unroll
    for (int n = 0; n < 8; ++n) acc1[n] = (f32x4){0.f, 0.f, 0.f, 0.f};

    #pragma unroll
    for (int half = 0; half < 2; ++half) {
        __syncthreads();
        for (int u = t; u < 2048; u += 256) {
            int r = u >> 4, c = u & 15;
            *(uint4*)(wlds + r * 272 + c * 16) =
                *(const uint4*)(Wc1 + (size_t)r * 256 + half * 128 + c * 8);
        }
        __syncthreads();
        const f16* A = half ? xb : aggx;
        #pragma unroll
        for (int ks = 0; ks < 4; ++ks) {
            f16x8 av = *(const f16x8*)(A + (size_t)arow * 128 + ks * 32 + kq);
            #pragma unroll
            for (int n = 0; n < 8; ++n) {
                f16x8 bv = *(const f16x8*)(wlds + (n * 16 + (l & 15)) * 272 + ks * 64 + kq * 2);
                acc1[n] = __builtin_amdgcn_mfma_f32_16x16x32_f16(av, bv, acc1[n], 0, 0, 0);
            }
        }
    }

    __syncthreads();
    #pragma unroll
    for (int n = 0; n < 8; ++n) {
        float bvb = b1[n * 16 + col];
        #pragma unroll
        for (int r = 0; r < 4; ++r) {
            f16 hv = (f16)fmaxf(acc1[n][r] + bvb, 0.f);
            *(f16*)(hlds + (lrow0 + r) * 272 + (n * 16 + col) * 2) = hv;
        }
    }
    __syncthreads();

    for (int u = t; u < 2048; u += 256) {
        int r = u >> 4, c = u & 15;
        *(uint4*)(wlds + r * 272 + c * 16) = *(const uint4*)(Wc2 + (size_t)r * 128 + c * 8);
    }
    __syncthreads();

    f32x4 acc2[8];
    #pragma unroll
    for (int n = 0; n < 8; ++n) acc2[n] = (f32x4){0.f, 0.f, 0.f, 0.f};
    #pragma unroll
    for (int ks = 0; ks < 4; ++ks) {
        f16x8 av = *(const f16x8*)(hlds + lrowA * 272 + (ks * 32 + kq) * 2);
        #pragma unroll
        for (int n = 0; n < 8; ++n) {
            f16x8 bv = *(const f16x8*)(wlds + (n * 16 + (l & 15)) * 272 + ks * 64 + kq * 2);
            acc2[n] = __builtin_amdgcn_mfma_f32_16x16x32_f16(av, bv, acc2[n], 0, 0, 0);
        }
    }

    int row0g = bm + lrow0;
    #pragma unroll
    for (int n = 0; n < 4; ++n) {
        #pragma unroll
        for (int r = 0; r < 4; ++r) {
            int gr = row0g + r;
            if (gr < M) hl2h[(size_t)gr * 64 + n * 16 + col] = (f16)acc2[n][r];
        }
    }
    #pragma unroll
    for (int n = 4; n < 8; ++n) {
        float bvb = b2[(n - 4) * 16 + col];
        #pragma unroll
        for (int r = 0; r < 4; ++r) {
            int gr = row0g + r;
            if (gr < M) outr16[(size_t)gr * 64 + (n - 4) * 16 + col] = (f16)(acc2[n][r] + bvb);
        }
    }
    __syncthreads();
    #pragma unroll
    for (int n = 0; n < 4; ++n) {
        #pragma unroll
        for (int r = 0; r < 4; ++r) {
            unsigned pk = __builtin_amdgcn_cvt_pk_fp8_f32(acc2[n][r], acc2[n][r], 0u, false);
            *(unsigned char*)(hlds + (lrow0 + r) * 64 + n * 16 + col) = (unsigned char)(pk & 0xFF);
        }
    }
    __syncthreads();
    {
        int rr = t >> 2, seg = t & 3;
        int gr = bm + rr;
        if (gr < M)
            *(uint4*)(hl28 + (size_t)gr * 64 + seg * 16) = *(const uint4*)(hlds + rr * 64 + seg * 16);
    }
}

// ---------------- agg2: persistent waves, 2 nodes/wave interleaved ----------------
// quarter-wave per edge: fl=lane&15 covers features 4fl..4fl+3 (dword fp8 / uint2 f16).

static __device__ __forceinline__ void agg2_one(const unsigned char* __restrict__ hl28,
                                                const f16* __restrict__ hl2,
                                                const int* __restrict__ csr,
                                                int s, int e, int q, int fl,
                                                f32x2& c01, f32x2& c23) {
    if (e - s >= 6) {
        int i = s + q;
        for (; i + 4 < e; i += 8) {
            unsigned v0 = *(const unsigned*)(hl28 + (size_t)csr[i] * 64 + fl * 4);
            unsigned v1 = *(const unsigned*)(hl28 + (size_t)csr[i + 4] * 64 + fl * 4);
            c01 += __builtin_amdgcn_cvt_pk_f32_fp8(v0, false);
            c23 += __builtin_amdgcn_cvt_pk_f32_fp8(v0, true);
            c01 += __builtin_amdgcn_cvt_pk_f32_fp8(v1, false);
            c23 += __builtin_amdgcn_cvt_pk_f32_fp8(v1, true);
        }
        for (; i < e; i += 4) {
            unsigned v0 = *(const unsigned*)(hl28 + (size_t)csr[i] * 64 + fl * 4);
            c01 += __builtin_amdgcn_cvt_pk_f32_fp8(v0, false);
            c23 += __builtin_amdgcn_cvt_pk_f32_fp8(v0, true);
        }
    } else {
        for (int i = s + q; i < e; i += 4) {
            uint2 v = *(const uint2*)(hl2 + (size_t)csr[i] * 64 + fl * 4);
            c01 += (f32x2){h2f_lo(v.x), h2f_hi(v.x)};
            c23 += (f32x2){h2f_lo(v.y), h2f_hi(v.y)};
        }
    }
}

__launch_bounds__(256)
__global__ void k_agg2f(const unsigned char* __restrict__ hl28,
                        const f16* __restrict__ hl2,
                        const f16* __restrict__ outr,
                        float* __restrict__ out,
                        const int* __restrict__ csr, const int* __restrict__ offs) {
    int wid = blockIdx.x * 4 + (threadIdx.x >> 6);
    int lane = threadIdx.x & 63;
    int q = lane >> 4, fl = lane & 15;

    for (int nA = wid * 2; nA < NN; nA += NAGW * 2) {     // NN even -> nA+1 always valid
        int sA = offs[nA], eA = offs[nA + 1], eB = offs[nA + 2];
        int sB = eA;
        f32x2 A01 = {0.f, 0.f}, A23 = {0.f, 0.f}, B01 = {0.f, 0.f}, B23 = {0.f, 0.f};

        if (eA - sA >= 6 && eB - sB >= 6) {
            int iA = sA + q, iB = sB + q;
            while (iA + 4 < eA && iB + 4 < eB) {
                unsigned va0 = *(const unsigned*)(hl28 + (size_t)csr[iA] * 64 + fl * 4);
                unsigned va1 = *(const unsigned*)(hl28 + (size_t)csr[iA + 4] * 64 + fl * 4);
                unsigned vb0 = *(const unsigned*)(hl28 + (size_t)csr[iB] * 64 + fl * 4);
                unsigned vb1 = *(const unsigned*)(hl28 + (size_t)csr[iB + 4] * 64 + fl * 4);
                A01 += __builtin_amdgcn_cvt_pk_f32_fp8(va0, false);
                A23 += __builtin_amdgcn_cvt_pk_f32_fp8(va0, true);
                A01 += __builtin_amdgcn_cvt_pk_f32_fp8(va1, false);
                A23 += __builtin_amdgcn_cvt_pk_f32_fp8(va1, true);
                B01 += __builtin_amdgcn_cvt_pk_f32_fp8(vb0, false);
                B23 += __builtin_amdgcn_cvt_pk_f32_fp8(vb0, true);
                B01 += __builtin_amdgcn_cvt_pk_f32_fp8(vb1, false);
                B23 += __builtin_amdgcn_cvt_pk_f32_fp8(vb1, true);
                iA += 8; iB += 8;
            }
            while (iA + 4 < eA) {
                unsigned va0 = *(const unsigned*)(hl28 + (size_t)csr[iA] * 64 + fl * 4);
                unsigned va1 = *(const unsigned*)(hl28 + (size_t)csr[iA + 4] * 64 + fl * 4);
                A01 += __builtin_amdgcn_cvt_pk_f32_fp8(va0, false);
                A23 += __builtin_amdgcn_cvt_pk_f32_fp8(va0, true);
                A01 += __builtin_amdgcn_cvt_pk_f32_fp8(va1, false);
                A23 += __builtin_amdgcn_cvt_pk_f32_fp8(va1, true);
                iA += 8;
            }
            while (iB + 4 < eB) {
                unsigned vb0 = *(const unsigned*)(hl28 + (size_t)csr[iB] * 64 + fl * 4);
                unsigned vb1 = *(const unsigned*)(hl28 + (size_t)csr[iB + 4] * 64 + fl * 4);
                B01 += __builtin_amdgcn_cvt_pk_f32_fp8(vb0, false);
                B23 += __builtin_amdgcn_cvt_pk_f32_fp8(vb0, true);
                B01 += __builtin_amdgcn_cvt_pk_f32_fp8(vb1, false);
                B23 += __builtin_amdgcn_cvt_pk_f32_fp8(vb1, true);
                iB += 8;
            }
            for (; iA < eA; iA += 4) {
                unsigned v = *(const unsigned*)(hl28 + (size_t)csr[iA] * 64 + fl * 4);
                A01 += __builtin_amdgcn_cvt_pk_f32_fp8(v, false);
                A23 += __builtin_amdgcn_cvt_pk_f32_fp8(v, true);
            }
            for (; iB < eB; iB += 4) {
                unsigned v = *(const unsigned*)(hl28 + (size_t)csr[iB] * 64 + fl * 4);
                B01 += __builtin_amdgcn_cvt_pk_f32_fp8(v, false);
                B23 += __builtin_amdgcn_cvt_pk_f32_fp8(v, true);
            }
        } else {
            agg2_one(hl28, hl2, csr, sA, eA, q, fl, A01, A23);
            agg2_one(hl28, hl2, csr, sB, eB, q, fl, B01, B23);
        }

        float a0 = A01[0], a1 = A01[1], a2 = A23[0], a3 = A23[1];
        float b0 = B01[0], b1 = B01[1], b2 = B23[0], b3 = B23[1];
        a0 += __shfl_xor(a0, 16, 64); a1 += __shfl_xor(a1, 16, 64);
        a2 += __shfl_xor(a2, 16, 64); a3 += __shfl_xor(a3, 16, 64);
        b0 += __shfl_xor(b0, 16, 64); b1 += __shfl_xor(b1, 16, 64);
        b2 += __shfl_xor(b2, 16, 64); b3 += __shfl_xor(b3, 16, 64);
        a0 += __shfl_xor(a0, 32, 64); a1 += __shfl_xor(a1, 32, 64);
        a2 += __shfl_xor(a2, 32, 64); a3 += __shfl_xor(a3, 32, 64);
        b0 += __shfl_xor(b0, 32, 64); b1 += __shfl_xor(b1, 32, 64);
        b2 += __shfl_xor(b2, 32, 64); b3 += __shfl_xor(b3, 32, 64);

        if (lane < 16) {
            float invA = 1.0f / fmaxf((float)(eA - sA), 1.0f);
            uint2 ro = *(const uint2*)(outr + (size_t)nA * 64 + fl * 4);
            float4 o;
            o.x = fmaf(a0, invA, h2f_lo(ro.x));
            o.y = fmaf(a1, invA, h2f_hi(ro.x));
            o.z = fmaf(a2, invA, h2f_lo(ro.y));
            o.w = fmaf(a3, invA, h2f_hi(ro.y));
            *(float4*)(out + (size_t)nA * 64 + fl * 4) = o;
            float invB = 1.0f / fmaxf((float)(eB - sB), 1.0f);
            uint2 rp = *(const uint2*)(outr + (size_t)(nA + 1) * 64 + fl * 4);
            float4 p;
            p.x = fmaf(b0, invB, h2f_lo(rp.x));
            p.y = fmaf(b1, invB, h2f_hi(rp.x));
            p.z = fmaf(b2, invB, h2f_lo(rp.y));
            p.w = fmaf(b3, invB, h2f_hi(rp.y));
            *(float4*)(out + (size_t)(nA + 1) * 64 + fl * 4) = p;
        }
    }
}

// ---------------- launch ----------------

extern "C" void kernel_launch(void* const* d_in, const int* in_sizes, int n_in,
                              void* d_out, int out_size, void* d_ws, size_t ws_size,
                              hipStream_t stream) {
    const float* x    = (const float*)d_in[0];
    const int* ei     = (const int*)d_in[1];   // int64 ref -> int32 at the harness boundary
    const float* w_l1 = (const float*)d_in[2];
    const float* w_r1 = (const float*)d_in[3];
    const float* b1   = (const float*)d_in[4];
    const float* w_l2 = (const float*)d_in[5];
    const float* w_r2 = (const float*)d_in[6];
    const float* b2   = (const float*)d_in[7];
    float* out        = (float*)d_out;

    const int* esrc = ei;
    const int* edst = ei + NE;

    // workspace layout (~110 MB)
    f16* xb     = (f16*)d_ws;                         // NN*128
    f16* aggx   = xb + (size_t)NN * 128;              // NN*128
    f16* hl2h   = aggx + (size_t)NN * 128;            // NN*64
    f16* outr16 = hl2h + (size_t)NN * 64;             // NN*64
    f16* Wc1    = outr16 + (size_t)NN * 64;           // 128*256
    f16* Wc2    = Wc1 + 128 * 256;                    // 128*128
    unsigned char* x8   = (unsigned char*)(Wc2 + 128 * 128);  // NN*128 fp8
    unsigned char* hl28 = x8 + (size_t)NN * 128;               // NN*64 fp8
    unsigned* pairs = (unsigned*)(hl28 + (size_t)NN * 64);     // NE
    int* csr    = (int*)(pairs + NE);                 // NE
    int* offs   = csr + NE;                           // NN+1
    int* rhist  = offs + NN + 1;                      // NR
    int* rstart = rhist + NR;                         // NR+1
    int* rcursor= rstart + NR + 1;                    // NR

    // ---- front: cvt x (f16+fp8) + build Wc1/Wc2 + region hist ----
    hipMemsetAsync(rhist, 0, NR * sizeof(int), stream);
    k_front<<<NBX + NBW1 + NBW2 + NTB, 256, 0, stream>>>(
        x, xb, x8, w_l1, w_r1, Wc1, w_l2, w_r2, Wc2, edst, rhist);

    // ---- CSR: scan -> tile-reserved scatter -> LDS sort ----
    k_rscan<<<1, 256, 0, stream>>>(rhist, rstart, rcursor, offs);
    k_passA<<<NTB, 256, 0, stream>>>(esrc, edst, rcursor, pairs, NE);
    k_passB<<<NR, 256, 0, stream>>>(pairs, rstart, csr, offs);

    // ---- layer 1 agg + fused GEMMs ----
    k_aggx<<<NAGB, 256, 0, stream>>>(x8, (unsigned*)aggx, csr, offs);
    k_gemm12<<<(NN + 63) / 64, 256, 0, stream>>>(aggx, xb, Wc1, b1, Wc2, b2,
                                                 hl2h, hl28, outr16, NN);

    // ---- layer 2 agg + combine ----
    k_agg2f<<<NAGB, 256, 0, stream>>>(hl28, hl2h, outr16, out, csr, offs);
}

// Round 14
// 187.197 us; speedup vs baseline: 1.1102x; 1.0019x over previous
//
#include <hip/hip_runtime.h>

#define NN 100000
#define NE 1600000
#define RSH 9                  // 512 nodes per region
#define NR ((NN + 511) >> 9)   // 196 regions
#define TILE 4096
#define NTB ((NE + TILE - 1) / TILE)  // 391 tiles
#define RCAP 10496             // region capacity (mean 8163)
#define NAGB 2048              // persistent agg blocks
#define NAGW (NAGB * 4)        // persistent agg waves

typedef _Float16 f16;
typedef _Float16 f16x8 __attribute__((ext_vector_type(8)));
typedef float f32x4 __attribute__((ext_vector_type(4)));
typedef float f32x2 __attribute__((ext_vector_type(2)));

static __device__ __forceinline__ float h2f_lo(unsigned v) {
    return (float)__builtin_bit_cast(_Float16, (unsigned short)(v & 0xffffu));
}
static __device__ __forceinline__ float h2f_hi(unsigned v) {
    return (float)__builtin_bit_cast(_Float16, (unsigned short)(v >> 16));
}
static __device__ __forceinline__ unsigned f2h_bits(float f) {
    return (unsigned)__builtin_bit_cast(unsigned short, (_Float16)f);
}

// ---------------- front mega-kernel: cvt x (f16 + fp8), build Wc1/Wc2, region hist ----------------

#define NBX 6250
#define NBW1 16
#define NBW2 8

__launch_bounds__(256)
__global__ void k_front(const float* __restrict__ x, f16* __restrict__ xb,
                        unsigned char* __restrict__ x8,
                        const float* __restrict__ w_l1, const float* __restrict__ w_r1,
                        f16* __restrict__ Wc1,
                        const float* __restrict__ w_l2, const float* __restrict__ w_r2,
                        f16* __restrict__ Wc2,
                        const int* __restrict__ dst, int* __restrict__ rhist) {
    __shared__ int lcnt[NR];
    int b = blockIdx.x, t = threadIdx.x;
    if (b < NBX) {
        int i = b * 2048 + t * 8;            // NN*128 = 12.8M = 6250*2048 exact
        float4 a = *(const float4*)(x + i);
        float4 c = *(const float4*)(x + i + 4);
        f16x8 v = { (f16)a.x, (f16)a.y, (f16)a.z, (f16)a.w,
                    (f16)c.x, (f16)c.y, (f16)c.z, (f16)c.w };
        *(f16x8*)(xb + i) = v;
        unsigned lo = __builtin_amdgcn_cvt_pk_fp8_f32(a.x, a.y, 0u, false);
        lo = __builtin_amdgcn_cvt_pk_fp8_f32(a.z, a.w, lo, true);
        unsigned hi = __builtin_amdgcn_cvt_pk_fp8_f32(c.x, c.y, 0u, false);
        hi = __builtin_amdgcn_cvt_pk_fp8_f32(c.z, c.w, hi, true);
        uint2 pk = make_uint2(lo, hi);
        *(uint2*)(x8 + i) = pk;
    } else if (b < NBX + NBW1) {
        int u = (b - NBX) * 2048 + t * 8;
        int o = u >> 8, k = u & 255;
        const float* srcp = (k < 128) ? (w_l1 + o * 128 + k) : (w_r1 + o * 128 + k - 128);
        float4 a = *(const float4*)(srcp);
        float4 c = *(const float4*)(srcp + 4);
        f16x8 v = { (f16)a.x, (f16)a.y, (f16)a.z, (f16)a.w,
                    (f16)c.x, (f16)c.y, (f16)c.z, (f16)c.w };
        *(f16x8*)(Wc1 + u) = v;
    } else if (b < NBX + NBW1 + NBW2) {
        int u = (b - NBX - NBW1) * 2048 + t * 8;
        int o = u >> 7, k = u & 127;
        const float* srcp = (o < 64) ? (w_l2 + o * 128 + k) : (w_r2 + (o - 64) * 128 + k);
        float4 a = *(const float4*)(srcp);
        float4 c = *(const float4*)(srcp + 4);
        f16x8 v = { (f16)a.x, (f16)a.y, (f16)a.z, (f16)a.w,
                    (f16)c.x, (f16)c.y, (f16)c.z, (f16)c.w };
        *(f16x8*)(Wc2 + u) = v;
    } else {
        int tb = b - NBX - NBW1 - NBW2;
        for (int i = t; i < NR; i += 256) lcnt[i] = 0;
        __syncthreads();
        int base = tb * TILE;
        int end = min(NE, base + TILE);
        for (int i = base + t; i < end; i += 256)
            atomicAdd(&lcnt[dst[i] >> RSH], 1);
        __syncthreads();
        for (int i = t; i < NR; i += 256)
            if (lcnt[i]) atomicAdd(&rhist[i], lcnt[i]);
    }
}

// ---------------- region scan ----------------

__global__ void k_rscan(const int* __restrict__ rhist, int* __restrict__ rstart,
                        int* __restrict__ rcursor, int* __restrict__ offs) {
    __shared__ int sh[256];
    int t = threadIdx.x;
    int v = (t < NR) ? rhist[t] : 0;
    sh[t] = v;
    __syncthreads();
    for (int off = 1; off < 256; off <<= 1) {
        int x = (t >= off) ? sh[t - off] : 0;
        __syncthreads();
        sh[t] += x;
        __syncthreads();
    }
    int excl = sh[t] - v;
    if (t < NR) { rstart[t] = excl; rcursor[t] = excl; }
    if (t == NR - 1) { rstart[NR] = excl + v; offs[NN] = NE; }
}

// ---------------- pass A: tile-reserved region scatter ----------------

__launch_bounds__(256)
__global__ void k_passA(const int* __restrict__ src, const int* __restrict__ dst,
                        int* __restrict__ rcursor, unsigned* __restrict__ pairs, int E) {
    __shared__ int lcnt[NR];
    __shared__ int lbase[NR];
    int t = threadIdx.x;
    int base = blockIdx.x * TILE;
    int end = min(E, base + TILE);
    for (int i = t; i < NR; i += 256) lcnt[i] = 0;
    __syncthreads();
    for (int i = base + t; i < end; i += 256)
        atomicAdd(&lcnt[dst[i] >> RSH], 1);
    __syncthreads();
    for (int i = t; i < NR; i += 256) {
        int c = lcnt[i];
        lbase[i] = c ? atomicAdd(&rcursor[i], c) : 0;
        lcnt[i] = 0;
    }
    __syncthreads();
    for (int i = base + t; i < end; i += 256) {
        int d = dst[i];
        int r = d >> RSH;
        int p = lbase[r] + atomicAdd(&lcnt[r], 1);
        pairs[p] = (unsigned)src[i] | ((unsigned)(d & 511) << 17);
    }
}

// ---------------- pass B: per-region LDS counting sort ----------------

__launch_bounds__(256)
__global__ void k_passB(const unsigned* __restrict__ pairs, const int* __restrict__ rstart,
                        int* __restrict__ csr, int* __restrict__ offs) {
    __shared__ unsigned buf[RCAP];
    __shared__ int buf2[RCAP];
    __shared__ int cnt[512];
    __shared__ int sc[256];
    int r = blockIdx.x, t = threadIdx.x;
    int s = rstart[r], e = rstart[r + 1];
    int n = e - s;
    for (int i = t; i < 512; i += 256) cnt[i] = 0;
    for (int i = t; i < n; i += 256) buf[i] = pairs[s + i];
    __syncthreads();
    for (int i = t; i < n; i += 256)
        atomicAdd(&cnt[(buf[i] >> 17) & 511], 1);
    __syncthreads();
    int c0 = cnt[2 * t], c1 = cnt[2 * t + 1];
    int mysum = c0 + c1;
    sc[t] = mysum;
    __syncthreads();
    for (int off = 1; off < 256; off <<= 1) {
        int x = (t >= off) ? sc[t - off] : 0;
        __syncthreads();
        sc[t] += x;
        __syncthreads();
    }
    int base0 = sc[t] - mysum;
    cnt[2 * t] = base0;
    cnt[2 * t + 1] = base0 + c0;
    int node = (r << RSH) + 2 * t;
    if (node < NN)     offs[node]     = s + base0;
    if (node + 1 < NN) offs[node + 1] = s + base0 + c0;
    __syncthreads();
    for (int i = t; i < n; i += 256) {
        unsigned u = buf[i];
        int p = atomicAdd(&cnt[(u >> 17) & 511], 1);
        buf2[p] = (int)(u & 0x1FFFF);
    }
    __syncthreads();
    for (int i = t; i < n; i += 256) csr[s + i] = buf2[i];
}

// ---------------- aggx: persistent waves, 2 nodes/wave interleaved (2 indep chains) ----------------
// quarter-wave per edge: q=lane>>4 edge phase, fl=lane&15 covers features 8fl..8fl+7 (uint2 fp8).

__launch_bounds__(256)
__global__ void k_aggx(const unsigned char* __restrict__ x8, unsigned* __restrict__ aggx,
                       const int* __restrict__ csr, const int* __restrict__ offs) {
    int wid = blockIdx.x * 4 + (threadIdx.x >> 6);
    int lane = threadIdx.x & 63;
    int q = lane >> 4, fl = lane & 15;

    for (int nA = wid * 2; nA < NN; nA += NAGW * 2) {     // NN even -> nA+1 always valid
        int sA = offs[nA], eA = offs[nA + 1], eB = offs[nA + 2];
        int sB = eA;

        f32x2 A0 = {0.f, 0.f}, A1 = {0.f, 0.f}, A2 = {0.f, 0.f}, A3 = {0.f, 0.f};
        f32x2 B0 = {0.f, 0.f}, B1 = {0.f, 0.f}, B2 = {0.f, 0.f}, B3 = {0.f, 0.f};

        int iA = sA + q, iB = sB + q;
        // fused main loop: 2-deep per node, two independent csr->row chains
        while (iA + 4 < eA && iB + 4 < eB) {
            int a0 = csr[iA], a1 = csr[iA + 4];
            int b0 = csr[iB], b1 = csr[iB + 4];
            uint2 va0 = *(const uint2*)(x8 + (size_t)a0 * 128 + fl * 8);
            uint2 va1 = *(const uint2*)(x8 + (size_t)a1 * 128 + fl * 8);
            uint2 vb0 = *(const uint2*)(x8 + (size_t)b0 * 128 + fl * 8);
            uint2 vb1 = *(const uint2*)(x8 + (size_t)b1 * 128 + fl * 8);
            A0 += __builtin_amdgcn_cvt_pk_f32_fp8(va0.x, false);
            A1 += __builtin_amdgcn_cvt_pk_f32_fp8(va0.x, true);
            A2 += __builtin_amdgcn_cvt_pk_f32_fp8(va0.y, false);
            A3 += __builtin_amdgcn_cvt_pk_f32_fp8(va0.y, true);
            A0 += __builtin_amdgcn_cvt_pk_f32_fp8(va1.x, false);
            A1 += __builtin_amdgcn_cvt_pk_f32_fp8(va1.x, true);
            A2 += __builtin_amdgcn_cvt_pk_f32_fp8(va1.y, false);
            A3 += __builtin_amdgcn_cvt_pk_f32_fp8(va1.y, true);
            B0 += __builtin_amdgcn_cvt_pk_f32_fp8(vb0.x, false);
            B1 += __builtin_amdgcn_cvt_pk_f32_fp8(vb0.x, true);
            B2 += __builtin_amdgcn_cvt_pk_f32_fp8(vb0.y, false);
            B3 += __builtin_amdgcn_cvt_pk_f32_fp8(vb0.y, true);
            B0 += __builtin_amdgcn_cvt_pk_f32_fp8(vb1.x, false);
            B1 += __builtin_amdgcn_cvt_pk_f32_fp8(vb1.x, true);
            B2 += __builtin_amdgcn_cvt_pk_f32_fp8(vb1.y, false);
            B3 += __builtin_amdgcn_cvt_pk_f32_fp8(vb1.y, true);
            iA += 8; iB += 8;
        }
        // leftover 2-deep single-node loops
        while (iA + 4 < eA) {
            int a0 = csr[iA], a1 = csr[iA + 4];
            uint2 va0 = *(const uint2*)(x8 + (size_t)a0 * 128 + fl * 8);
            uint2 va1 = *(const uint2*)(x8 + (size_t)a1 * 128 + fl * 8);
            A0 += __builtin_amdgcn_cvt_pk_f32_fp8(va0.x, false);
            A1 += __builtin_amdgcn_cvt_pk_f32_fp8(va0.x, true);
            A2 += __builtin_amdgcn_cvt_pk_f32_fp8(va0.y, false);
            A3 += __builtin_amdgcn_cvt_pk_f32_fp8(va0.y, true);
            A0 += __builtin_amdgcn_cvt_pk_f32_fp8(va1.x, false);
            A1 += __builtin_amdgcn_cvt_pk_f32_fp8(va1.x, true);
            A2 += __builtin_amdgcn_cvt_pk_f32_fp8(va1.y, false);
            A3 += __builtin_amdgcn_cvt_pk_f32_fp8(va1.y, true);
            iA += 8;
        }
        while (iB + 4 < eB) {
            int b0 = csr[iB], b1 = csr[iB + 4];
            uint2 vb0 = *(const uint2*)(x8 + (size_t)b0 * 128 + fl * 8);
            uint2 vb1 = *(const uint2*)(x8 + (size_t)b1 * 128 + fl * 8);
            B0 += __builtin_amdgcn_cvt_pk_f32_fp8(vb0.x, false);
            B1 += __builtin_amdgcn_cvt_pk_f32_fp8(vb0.x, true);
            B2 += __builtin_amdgcn_cvt_pk_f32_fp8(vb0.y, false);
            B3 += __builtin_amdgcn_cvt_pk_f32_fp8(vb0.y, true);
            B0 += __builtin_amdgcn_cvt_pk_f32_fp8(vb1.x, false);
            B1 += __builtin_amdgcn_cvt_pk_f32_fp8(vb1.x, true);
            B2 += __builtin_amdgcn_cvt_pk_f32_fp8(vb1.y, false);
            B3 += __builtin_amdgcn_cvt_pk_f32_fp8(vb1.y, true);
            iB += 8;
        }
        for (; iA < eA; iA += 4) {
            uint2 v = *(const uint2*)(x8 + (size_t)csr[iA] * 128 + fl * 8);
            A0 += __builtin_amdgcn_cvt_pk_f32_fp8(v.x, false);
            A1 += __builtin_amdgcn_cvt_pk_f32_fp8(v.x, true);
            A2 += __builtin_amdgcn_cvt_pk_f32_fp8(v.y, false);
            A3 += __builtin_amdgcn_cvt_pk_f32_fp8(v.y, true);
        }
        for (; iB < eB; iB += 4) {
            uint2 v = *(const uint2*)(x8 + (size_t)csr[iB] * 128 + fl * 8);
            B0 += __builtin_amdgcn_cvt_pk_f32_fp8(v.x, false);
            B1 += __builtin_amdgcn_cvt_pk_f32_fp8(v.x, true);
            B2 += __builtin_amdgcn_cvt_pk_f32_fp8(v.y, false);
            B3 += __builtin_amdgcn_cvt_pk_f32_fp8(v.y, true);
        }

        float a0 = A0[0], a1 = A0[1], a2 = A1[0], a3 = A1[1];
        float a4 = A2[0], a5 = A2[1], a6 = A3[0], a7 = A3[1];
        float b0 = B0[0], b1 = B0[1], b2 = B1[0], b3 = B1[1];
        float b4 = B2[0], b5 = B2[1], b6 = B3[0], b7 = B3[1];
        a0 += __shfl_xor(a0, 16, 64); a1 += __shfl_xor(a1, 16, 64);
        a2 += __shfl_xor(a2, 16, 64); a3 += __shfl_xor(a3, 16, 64);
        a4 += __shfl_xor(a4, 16, 64); a5 += __shfl_xor(a5, 16, 64);
        a6 += __shfl_xor(a6, 16, 64); a7 += __shfl_xor(a7, 16, 64);
        b0 += __shfl_xor(b0, 16, 64); b1 += __shfl_xor(b1, 16, 64);
        b2 += __shfl_xor(b2, 16, 64); b3 += __shfl_xor(b3, 16, 64);
        b4 += __shfl_xor(b4, 16, 64); b5 += __shfl_xor(b5, 16, 64);
        b6 += __shfl_xor(b6, 16, 64); b7 += __shfl_xor(b7, 16, 64);
        a0 += __shfl_xor(a0, 32, 64); a1 += __shfl_xor(a1, 32, 64);
        a2 += __shfl_xor(a2, 32, 64); a3 += __shfl_xor(a3, 32, 64);
        a4 += __shfl_xor(a4, 32, 64); a5 += __shfl_xor(a5, 32, 64);
        a6 += __shfl_xor(a6, 32, 64); a7 += __shfl_xor(a7, 32, 64);
        b0 += __shfl_xor(b0, 32, 64); b1 += __shfl_xor(b1, 32, 64);
        b2 += __shfl_xor(b2, 32, 64); b3 += __shfl_xor(b3, 32, 64);
        b4 += __shfl_xor(b4, 32, 64); b5 += __shfl_xor(b5, 32, 64);
        b6 += __shfl_xor(b6, 32, 64); b7 += __shfl_xor(b7, 32, 64);

        if (lane < 16) {
            float invA = 1.0f / fmaxf((float)(eA - sA), 1.0f);
            uint4 w;
            w.x = f2h_bits(a0 * invA) | (f2h_bits(a1 * invA) << 16);
            w.y = f2h_bits(a2 * invA) | (f2h_bits(a3 * invA) << 16);
            w.z = f2h_bits(a4 * invA) | (f2h_bits(a5 * invA) << 16);
            w.w = f2h_bits(a6 * invA) | (f2h_bits(a7 * invA) << 16);
            *(uint4*)(aggx + (size_t)nA * 64 + fl * 4) = w;
            float invB = 1.0f / fmaxf((float)(eB - sB), 1.0f);
            uint4 u;
            u.x = f2h_bits(b0 * invB) | (f2h_bits(b1 * invB) << 16);
            u.y = f2h_bits(b2 * invB) | (f2h_bits(b3 * invB) << 16);
            u.z = f2h_bits(b4 * invB) | (f2h_bits(b5 * invB) << 16);
            u.w = f2h_bits(b6 * invB) | (f2h_bits(b7 * invB) << 16);
            *(uint4*)(aggx + (size_t)(nA + 1) * 64 + fl * 4) = u;
        }
    }
}

// ---------------- fused GEMM1+GEMM2 (unchanged) ----------------

__launch_bounds__(256)
__global__ void k_gemm12(const f16* __restrict__ aggx, const f16* __restrict__ xb,
                         const f16* __restrict__ Wc1, const float* __restrict__ b1,
                         const f16* __restrict__ Wc2, const float* __restrict__ b2,
                         f16* __restrict__ hl2h, unsigned char* __restrict__ hl28,
                         f16* __restrict__ outr16, int M) {
    __shared__ __align__(16) char wlds[128 * 272];
    __shared__ __align__(16) char hlds[64 * 272];
    int t = threadIdx.x;
    int l = t & 63;
    int wid = t >> 6;
    int bm = blockIdx.x * 64;
    int arow = bm + wid * 16 + (l & 15);
    if (arow >= M) arow = M - 1;
    int kq = (l >> 4) * 8;
    int col = l & 15;
    int lrow0 = wid * 16 + ((l >> 4) << 2);
    int lrowA = wid * 16 + (l & 15);

    f32x4 acc1[8];
    #pragma unroll
    for (int n = 0; n < 8; ++n) acc1[n] = (f32x4){0.f, 0.f, 0.f, 0.f};

    #pragma unroll
    for (int half = 0; half < 2; ++half) {
        __syncthreads();
        for (int u = t; u < 2048; u += 256) {
            int r = u >> 4, c = u & 15;
            *(uint4*)(wlds + r * 272 + c * 16) =
                *(const uint4*)(Wc1 + (size_t)r * 256 + half * 128 + c * 8);
        }
        __syncthreads();
        const f16* A = half ? xb : aggx;
        #pragma unroll
        for (int ks = 0; ks < 4; ++ks) {
            f16x8 av = *(const f16x8*)(A + (size_t)arow * 128 + ks * 32 + kq);
            #pragma unroll
            for (int n = 0; n < 8; ++n) {
                f16x8 bv = *(const f16x8*)(wlds + (n * 16 + (l & 15)) * 272 + ks * 64 + kq * 2);
                acc1[n] = __builtin_amdgcn_mfma_f32_16x16x32_f16(av, bv, acc1[n], 0, 0, 0);
            }
        }
    }

    __syncthreads();
    #pragma unroll
    for (int n = 0; n < 8; ++n) {
        float bvb = b1[n * 16 + col];
        #pragma unroll
        for (int r = 0; r < 4; ++r) {
            f16 hv = (f16)fmaxf(acc1[n][r] + bvb, 0.f);
            *(f16*)(hlds + (lrow0 + r) * 272 + (n * 16 + col) * 2) = hv;
        }
    }
    __syncthreads();

    for (int u = t; u < 2048; u += 256) {
        int r = u >> 4, c = u & 15;
        *(uint4*)(wlds + r * 272 + c * 16) = *(const uint4*)(Wc2 + (size_t)r * 128 + c * 8);
    }
    __syncthreads();

    f32x4 acc2[8];
    #pragma unroll
    for (int n = 0; n < 8; ++n) acc2[n] = (f32x4){0.f, 0.f, 0.f, 0.f};
    #pragma unroll
    for (int ks = 0; ks < 4; ++ks) {
        f16x8 av = *(const f16x8*)(hlds + lrowA * 272 + (ks * 32 + kq) * 2);
        #pragma unroll
        for (int n = 0; n < 8; ++n) {
            f16x8 bv = *(const f16x8*)(wlds + (n * 16 + (l & 15)) * 272 + ks * 64 + kq * 2);
            acc2[n] = __builtin_amdgcn_mfma_f32_16x16x32_f16(av, bv, acc2[n], 0, 0, 0);
        }
    }

    int row0g = bm + lrow0;
    #pragma unroll
    for (int n = 0; n < 4; ++n) {
        #pragma unroll
        for (int r = 0; r < 4; ++r) {
            int gr = row0g + r;
            if (gr < M) hl2h[(size_t)gr * 64 + n * 16 + col] = (f16)acc2[n][r];
        }
    }
    #pragma unroll
    for (int n = 4; n < 8; ++n) {
        float bvb = b2[(n - 4) * 16 + col];
        #pragma unroll
        for (int r = 0; r < 4; ++r) {
            int gr = row0g + r;
            if (gr < M) outr16[(size_t)gr * 64 + (n - 4) * 16 + col] = (f16)(acc2[n][r] + bvb);
        }
    }
    __syncthreads();
    #pragma unroll
    for (int n = 0; n < 4; ++n) {
        #pragma unroll
        for (int r = 0; r < 4; ++r) {
            unsigned pk = __builtin_amdgcn_cvt_pk_fp8_f32(acc2[n][r], acc2[n][r], 0u, false);
            *(unsigned char*)(hlds + (lrow0 + r) * 64 + n * 16 + col) = (unsigned char)(pk & 0xFF);
        }
    }
    __syncthreads();
    {
        int rr = t >> 2, seg = t & 3;
        int gr = bm + rr;
        if (gr < M)
            *(uint4*)(hl28 + (size_t)gr * 64 + seg * 16) = *(const uint4*)(hlds + rr * 64 + seg * 16);
    }
}

// ---------------- agg2: persistent waves, 2 nodes/wave interleaved ----------------
// quarter-wave per edge: fl=lane&15 covers features 4fl..4fl+3 (dword fp8 / uint2 f16).

static __device__ __forceinline__ void agg2_one(const unsigned char* __restrict__ hl28,
                                                const f16* __restrict__ hl2,
                                                const int* __restrict__ csr,
                                                int s, int e, int q, int fl,
                                                f32x2& c01, f32x2& c23) {
    if (e - s >= 6) {
        int i = s + q;
        for (; i + 4 < e; i += 8) {
            unsigned v0 = *(const unsigned*)(hl28 + (size_t)csr[i] * 64 + fl * 4);
            unsigned v1 = *(const unsigned*)(hl28 + (size_t)csr[i + 4] * 64 + fl * 4);
            c01 += __builtin_amdgcn_cvt_pk_f32_fp8(v0, false);
            c23 += __builtin_amdgcn_cvt_pk_f32_fp8(v0, true);
            c01 += __builtin_amdgcn_cvt_pk_f32_fp8(v1, false);
            c23 += __builtin_amdgcn_cvt_pk_f32_fp8(v1, true);
        }
        for (; i < e; i += 4) {
            unsigned v0 = *(const unsigned*)(hl28 + (size_t)csr[i] * 64 + fl * 4);
            c01 += __builtin_amdgcn_cvt_pk_f32_fp8(v0, false);
            c23 += __builtin_amdgcn_cvt_pk_f32_fp8(v0, true);
        }
    } else {
        for (int i = s + q; i < e; i += 4) {
            uint2 v = *(const uint2*)(hl2 + (size_t)csr[i] * 64 + fl * 4);
            c01 += (f32x2){h2f_lo(v.x), h2f_hi(v.x)};
            c23 += (f32x2){h2f_lo(v.y), h2f_hi(v.y)};
        }
    }
}

__launch_bounds__(256)
__global__ void k_agg2f(const unsigned char* __restrict__ hl28,
                        const f16* __restrict__ hl2,
                        const f16* __restrict__ outr,
                        float* __restrict__ out,
                        const int* __restrict__ csr, const int* __restrict__ offs) {
    int wid = blockIdx.x * 4 + (threadIdx.x >> 6);
    int lane = threadIdx.x & 63;
    int q = lane >> 4, fl = lane & 15;

    for (int nA = wid * 2; nA < NN; nA += NAGW * 2) {     // NN even -> nA+1 always valid
        int sA = offs[nA], eA = offs[nA + 1], eB = offs[nA + 2];
        int sB = eA;
        f32x2 A01 = {0.f, 0.f}, A23 = {0.f, 0.f}, B01 = {0.f, 0.f}, B23 = {0.f, 0.f};

        if (eA - sA >= 6 && eB - sB >= 6) {
            int iA = sA + q, iB = sB + q;
            while (iA + 4 < eA && iB + 4 < eB) {
                unsigned va0 = *(const unsigned*)(hl28 + (size_t)csr[iA] * 64 + fl * 4);
                unsigned va1 = *(const unsigned*)(hl28 + (size_t)csr[iA + 4] * 64 + fl * 4);
                unsigned vb0 = *(const unsigned*)(hl28 + (size_t)csr[iB] * 64 + fl * 4);
                unsigned vb1 = *(const unsigned*)(hl28 + (size_t)csr[iB + 4] * 64 + fl * 4);
                A01 += __builtin_amdgcn_cvt_pk_f32_fp8(va0, false);
                A23 += __builtin_amdgcn_cvt_pk_f32_fp8(va0, true);
                A01 += __builtin_amdgcn_cvt_pk_f32_fp8(va1, false);
                A23 += __builtin_amdgcn_cvt_pk_f32_fp8(va1, true);
                B01 += __builtin_amdgcn_cvt_pk_f32_fp8(vb0, false);
                B23 += __builtin_amdgcn_cvt_pk_f32_fp8(vb0, true);
                B01 += __builtin_amdgcn_cvt_pk_f32_fp8(vb1, false);
                B23 += __builtin_amdgcn_cvt_pk_f32_fp8(vb1, true);
                iA += 8; iB += 8;
            }
            while (iA + 4 < eA) {
                unsigned va0 = *(const unsigned*)(hl28 + (size_t)csr[iA] * 64 + fl * 4);
                unsigned va1 = *(const unsigned*)(hl28 + (size_t)csr[iA + 4] * 64 + fl * 4);
                A01 += __builtin_amdgcn_cvt_pk_f32_fp8(va0, false);
                A23 += __builtin_amdgcn_cvt_pk_f32_fp8(va0, true);
                A01 += __builtin_amdgcn_cvt_pk_f32_fp8(va1, false);
                A23 += __builtin_amdgcn_cvt_pk_f32_fp8(va1, true);
                iA += 8;
            }
            while (iB + 4 < eB) {
                unsigned vb0 = *(const unsigned*)(hl28 + (size_t)csr[iB] * 64 + fl * 4);
                unsigned vb1 = *(const unsigned*)(hl28 + (size_t)csr[iB + 4] * 64 + fl * 4);
                B01 += __builtin_amdgcn_cvt_pk_f32_fp8(vb0, false);
                B23 += __builtin_amdgcn_cvt_pk_f32_fp8(vb0, true);
                B01 += __builtin_amdgcn_cvt_pk_f32_fp8(vb1, false);
                B23 += __builtin_amdgcn_cvt_pk_f32_fp8(vb1, true);
                iB += 8;
            }
            for (; iA < eA; iA += 4) {
                unsigned v = *(const unsigned*)(hl28 + (size_t)csr[iA] * 64 + fl * 4);
                A01 += __builtin_amdgcn_cvt_pk_f32_fp8(v, false);
                A23 += __builtin_amdgcn_cvt_pk_f32_fp8(v, true);
            }
            for (; iB < eB; iB += 4) {
                unsigned v = *(const unsigned*)(hl28 + (size_t)csr[iB] * 64 + fl * 4);
                B01 += __builtin_amdgcn_cvt_pk_f32_fp8(v, false);
                B23 += __builtin_amdgcn_cvt_pk_f32_fp8(v, true);
            }
        } else {
            agg2_one(hl28, hl2, csr, sA, eA, q, fl, A01, A23);
            agg2_one(hl28, hl2, csr, sB, eB, q, fl, B01, B23);
        }

        float a0 = A01[0], a1 = A01[1], a2 = A23[0], a3 = A23[1];
        float b0 = B01[0], b1 = B01[1], b2 = B23[0], b3 = B23[1];
        a0 += __shfl_xor(a0, 16, 64); a1 += __shfl_xor(a1, 16, 64);
        a2 += __shfl_xor(a2, 16, 64); a3 += __shfl_xor(a3, 16, 64);
        b0 += __shfl_xor(b0, 16, 64); b1 += __shfl_xor(b1, 16, 64);
        b2 += __shfl_xor(b2, 16, 64); b3 += __shfl_xor(b3, 16, 64);
        a0 += __shfl_xor(a0, 32, 64); a1 += __shfl_xor(a1, 32, 64);
        a2 += __shfl_xor(a2, 32, 64); a3 += __shfl_xor(a3, 32, 64);
        b0 += __shfl_xor(b0, 32, 64); b1 += __shfl_xor(b1, 32, 64);
        b2 += __shfl_xor(b2, 32, 64); b3 += __shfl_xor(b3, 32, 64);

        if (lane < 16) {
            float invA = 1.0f / fmaxf((float)(eA - sA), 1.0f);
            uint2 ro = *(const uint2*)(outr + (size_t)nA * 64 + fl * 4);
            float4 o;
            o.x = fmaf(a0, invA, h2f_lo(ro.x));
            o.y = fmaf(a1, invA, h2f_hi(ro.x));
            o.z = fmaf(a2, invA, h2f_lo(ro.y));
            o.w = fmaf(a3, invA, h2f_hi(ro.y));
            *(float4*)(out + (size_t)nA * 64 + fl * 4) = o;
            float invB = 1.0f / fmaxf((float)(eB - sB), 1.0f);
            uint2 rp = *(const uint2*)(outr + (size_t)(nA + 1) * 64 + fl * 4);
            float4 p;
            p.x = fmaf(b0, invB, h2f_lo(rp.x));
            p.y = fmaf(b1, invB, h2f_hi(rp.x));
            p.z = fmaf(b2, invB, h2f_lo(rp.y));
            p.w = fmaf(b3, invB, h2f_hi(rp.y));
            *(float4*)(out + (size_t)(nA + 1) * 64 + fl * 4) = p;
        }
    }
}

// ---------------- launch ----------------

extern "C" void kernel_launch(void* const* d_in, const int* in_sizes, int n_in,
                              void* d_out, int out_size, void* d_ws, size_t ws_size,
                              hipStream_t stream) {
    const float* x    = (const float*)d_in[0];
    const int* ei     = (const int*)d_in[1];   // int64 ref -> int32 at the harness boundary
    const float* w_l1 = (const float*)d_in[2];
    const float* w_r1 = (const float*)d_in[3];
    const float* b1   = (const float*)d_in[4];
    const float* w_l2 = (const float*)d_in[5];
    const float* w_r2 = (const float*)d_in[6];
    const float* b2   = (const float*)d_in[7];
    float* out        = (float*)d_out;

    const int* esrc = ei;
    const int* edst = ei + NE;

    // workspace layout (~110 MB)
    f16* xb     = (f16*)d_ws;                         // NN*128
    f16* aggx   = xb + (size_t)NN * 128;              // NN*128
    f16* hl2h   = aggx + (size_t)NN * 128;            // NN*64
    f16* outr16 = hl2h + (size_t)NN * 64;             // NN*64
    f16* Wc1    = outr16 + (size_t)NN * 64;           // 128*256
    f16* Wc2    = Wc1 + 128 * 256;                    // 128*128
    unsigned char* x8   = (unsigned char*)(Wc2 + 128 * 128);  // NN*128 fp8
    unsigned char* hl28 = x8 + (size_t)NN * 128;               // NN*64 fp8
    unsigned* pairs = (unsigned*)(hl28 + (size_t)NN * 64);     // NE
    int* csr    = (int*)(pairs + NE);                 // NE
    int* offs   = csr + NE;                           // NN+1
    int* rhist  = offs + NN + 1;                      // NR
    int* rstart = rhist + NR;                         // NR+1
    int* rcursor= rstart + NR + 1;                    // NR

    // ---- front: cvt x (f16+fp8) + build Wc1/Wc2 + region hist ----
    hipMemsetAsync(rhist, 0, NR * sizeof(int), stream);
    k_front<<<NBX + NBW1 + NBW2 + NTB, 256, 0, stream>>>(
        x, xb, x8, w_l1, w_r1, Wc1, w_l2, w_r2, Wc2, edst, rhist);

    // ---- CSR: scan -> tile-reserved scatter -> LDS sort ----
    k_rscan<<<1, 256, 0, stream>>>(rhist, rstart, rcursor, offs);
    k_passA<<<NTB, 256, 0, stream>>>(esrc, edst, rcursor, pairs, NE);
    k_passB<<<NR, 256, 0, stream>>>(pairs, rstart, csr, offs);

    // ---- layer 1 agg + fused GEMMs ----
    k_aggx<<<NAGB, 256, 0, stream>>>(x8, (unsigned*)aggx, csr, offs);
    k_gemm12<<<(NN + 63) / 64, 256, 0, stream>>>(aggx, xb, Wc1, b1, Wc2, b2,
                                                 hl2h, hl28, outr16, NN);

    // ---- layer 2 agg + combine ----
    k_agg2f<<<NAGB, 256, 0, stream>>>(hl28, hl2h, outr16, out, csr, offs);
}